// Round 2
// baseline (435.597 us; speedup 1.0000x reference)
//
#include <hip/hip_runtime.h>
#include <stdint.h>

// Problem constants: B=32, T=4096, Dq=Dk=512, A=512
#define DQ 512
#define DK 512
#define NA 512
#define NBATCH 32
#define M_TOTAL (NBATCH * 4096)

#define BM 128
#define BK 32
#define KITERS (DK / BK)                 // 16
#define NBLK 256                         // persistent blocks, 1 per CU
#define ROUNDS (M_TOTAL / (BM * NBLK))   // 4 m-tiles per block
#define NT (ROUNDS * KITERS)             // 64 pipeline steps

typedef __attribute__((ext_vector_type(8))) short bf16x8;   // MFMA A/B frag (4 VGPRs)
typedef __attribute__((ext_vector_type(4))) float f32x4;    // MFMA C/D frag

// async global->LDS, 16B/lane. LDS dst = wave-uniform base + lane*16.
__device__ __forceinline__ void gll16(const void* g, void* l) {
  __builtin_amdgcn_global_load_lds(
      (const __attribute__((address_space(1))) uint32_t*)g,
      (__attribute__((address_space(3))) uint32_t*)l, 16, 0, 0);
}

// fp32 pair -> packed bf16 (round-half-up): 2 adds + v_perm_b32.
__device__ __forceinline__ uint32_t pack2bf16(float a, float b) {
  uint32_t ua = __float_as_uint(a) + 0x8000u;
  uint32_t ub = __float_as_uint(b) + 0x8000u;
  return __builtin_amdgcn_perm(ub, ua, 0x07060302);   // {ub.hi16 : ua.hi16}
}

// fast tanh: 1 - 2/(e^{2x}+1); correct limits at +/-inf
__device__ __forceinline__ float fast_tanh(float x) {
  float e = __expf(2.0f * x);
  return 1.0f - 2.0f * __builtin_amdgcn_rcpf(e + 1.0f);
}

// --- prep: W-transpose -> K-blocked tiled bf16 (blocks 0..63) +
//           qpb = q@Wq + b, spread over 256 blocks (blocks 64..319) ---
// Tiled layout: WkTt[(d>>5)*16384 + n*32 + (d&31)] = bf16(W[512+d][n])
__global__ void prep_kernel(const float* __restrict__ W,
                            const float* __restrict__ q,
                            const float* __restrict__ bias,
                            uint16_t* __restrict__ WkTt,
                            float* __restrict__ qpb) {
  const int tid = threadIdx.x;
  if (blockIdx.x < 64) {
    __shared__ uint16_t T[64][65];
    const int d0 = (blockIdx.x & 7) * 64;
    const int a0 = (blockIdx.x >> 3) * 64;
#pragma unroll
    for (int j = 0; j < 16; ++j) {
      int dd = j * 4 + (tid >> 6);
      int aa = tid & 63;   // coalesced read
      uint32_t u = __float_as_uint(W[(size_t)(DQ + d0 + dd) * NA + a0 + aa]) + 0x8000u;
      T[dd][aa] = (uint16_t)(u >> 16);
    }
    __syncthreads();
#pragma unroll
    for (int j = 0; j < 8; ++j) {
      int aa = j * 8 + (tid >> 5);
      int n  = a0 + aa;
      int dp = (tid & 31) * 2;
      int d  = d0 + dp;
      uint32_t val = (uint32_t)T[dp][aa] | ((uint32_t)T[dp + 1][aa] << 16);
      *(uint32_t*)(WkTt + (size_t)(d >> 5) * 16384 + n * 32 + (d & 31)) = val;
    }
  } else {
    // qpb: one block per (batch, 64-col chunk); 4 waves x 128-d partials
    __shared__ float pr[4][64];
    const int bb  = blockIdx.x - 64;        // 0..255
    const int b   = bb >> 3;                // batch
    const int a0  = (bb & 7) * 64;          // col chunk
    const int al  = tid & 63;
    const int seg = tid >> 6;               // 4 d-segments of 128
    const float* qr = q + b * DQ + seg * 128;               // wave-uniform -> scalar
    const float* wp = W + (size_t)(seg * 128) * NA + a0 + al;
    float acc = 0.f;
#pragma unroll 8
    for (int i = 0; i < 128; ++i)
      acc = fmaf(qr[i], wp[(size_t)i * NA], acc);
    pr[seg][al] = acc;
    __syncthreads();
    if (tid < 64) {
      float s = bias[a0 + tid] + pr[0][tid] + pr[1][tid] + pr[2][tid] + pr[3][tid];
      qpb[b * NA + a0 + tid] = s;
    }
  }
}

// --- fused persistent-block GEMM (128x512 tile, bf16 MFMA) + tanh + v-dot ---
// 8 waves, wave tile 64x128 (2 row-groups x 4 col-groups): LDS frag reads
// 96 KB/step (vs 128 KB at 16x 64x64 waves) -> LDS under HBM pace.
// Triple-buffered B (global_load_lds, depth-2), double-buffered A (reg->pack->
// ds_write, depth-2), raw s_barrier with COUNTED s_waitcnt vmcnt(4).
// FIFO at top of step t: [B(t):4, A(t+1):2, B(t+1):4] -> vmcnt(4) drains
// {B(t), A(t+1)}, leaves B(t+1) in flight. Issue order: A first, then B.
// Epilogue loads/stores are younger -> vmcnt(4) still safe (over-drains only).
__global__ __launch_bounds__(512, 2)
void score_kernel(const float* __restrict__ Kmat,        // fp32 [M_TOTAL, DK]
                  const uint16_t* __restrict__ WkTt,     // tiled bf16 [16][512][32]
                  const float* __restrict__ qpb,         // fp32 [NBATCH, NA]
                  const float* __restrict__ v,           // fp32 [NA]
                  float* __restrict__ out) {             // fp32 [M_TOTAL]
  __shared__ __align__(16) uint16_t Bs[3 * NA * BK];     // 96 KB triple buffer
  __shared__ __align__(16) uint16_t As[2 * BM * BK];     // 16 KB double buffer
  __shared__ float part[4][BM];                          // 2 KB

  const int tid  = threadIdx.x;
  const int lane = tid & 63;
  const int w    = tid >> 6;       // 8 waves: 2 row-groups x 4 col-groups
  const int wc   = w & 3;          // col group -> cols wc*128 .. +127
  const int wr   = w >> 2;         // row group -> rows wr*64 .. +63
  const int r16  = lane & 15;
  const int quad = lane >> 4;
  const int sw   = quad ^ ((r16 >> 1) & 3);   // granule swizzle slot (2-way max = free)
  const int bid  = blockIdx.x;

  // ---- B-DMA lane constants: 4 granules (16 B) per thread per step ----
  const uint16_t* bconst[4];
#pragma unroll
  for (int j = 0; j < 4; ++j) {
    int s = j * 512 + tid;                       // LDS-linear granule id
    int n = s >> 2;
    int k = (s & 3) ^ ((n >> 1) & 3);            // inverse swizzle at source
    bconst[j] = WkTt + n * 32 + k * 8;
  }
  const int bdst[4] = { (0 * 512 + w * 64) * 16, (1 * 512 + w * 64) * 16,
                        (2 * 512 + w * 64) * 16, (3 * 512 + w * 64) * 16 };

  // ---- A staging: 8 k-elems of one row per thread (2x float4, coalesced) ----
  const int arow = tid >> 2;                     // 0..127
  const int qk   = tid & 3;                      // k-quarter
  const int rs   = (arow >> 1) & 3;
  const int ao0  = arow * 64 + (((qk >> 1) ^ rs) * 16) + (qk & 1) * 8;       // gran qk>>1
  const int ao1  = arow * 64 + (((2 + (qk >> 1)) ^ rs) * 16) + (qk & 1) * 8; // gran 2+(qk>>1)
  const float* ap = Kmat + (size_t)bid * BM * DK + (size_t)arow * DK + qk * 4;

  // ---- fragment read byte offsets (swizzled) ----
  const int a_ro = (wr * 64 + r16) * 64 + sw * 16;    // + ms*1024
  const int b_ro = (wc * 128 + r16) * 64 + sw * 16;   // + ns*1024

  f32x4 acc[4][8];
#pragma unroll
  for (int i = 0; i < 4; ++i)
#pragma unroll
    for (int j = 0; j < 8; ++j) { f32x4 z = {0.f, 0.f, 0.f, 0.f}; acc[i][j] = z; }

  float vv[8];
#pragma unroll
  for (int ns = 0; ns < 8; ++ns) vv[ns] = v[wc * 128 + ns * 16 + r16];

  // ---- prologue: establish FIFO [B0:4, A1:2, B1:4] ----
  float4 c0 = *(const float4*)ap;                // A(0) k 0..15 quarter
  float4 c1 = *(const float4*)(ap + 16);         // A(0) k 16..31 quarter
  ap += BK;
#pragma unroll
  for (int j = 0; j < 4; ++j)                    // B(0)
    gll16((const void*)bconst[j], (void*)((char*)Bs + bdst[j]));
  asm volatile("s_waitcnt vmcnt(4)" ::: "memory");   // A(0) done
  {
    uint2 p0, p1;
    p0.x = pack2bf16(c0.x, c0.y); p0.y = pack2bf16(c0.z, c0.w);
    p1.x = pack2bf16(c1.x, c1.y); p1.y = pack2bf16(c1.z, c1.w);
    *(uint2*)((char*)As + ao0) = p0;
    *(uint2*)((char*)As + ao1) = p1;
  }
  c0 = *(const float4*)ap;                       // A(1)
  c1 = *(const float4*)(ap + 16);
  ap += BK;
#pragma unroll
  for (int j = 0; j < 4; ++j)                    // B(1)
    gll16((const void*)(bconst[j] + 16384), (void*)((char*)Bs + 32768 + bdst[j]));

  int rdB = 0;   // t % 3
#pragma unroll 1
  for (int t = 0; t < NT; ++t) {
    // counted drain: B(t)+A(t+1) complete; B(t+1) stays in flight (never 0 mid-loop)
    if (t < NT - 1)
      asm volatile("s_waitcnt vmcnt(4) lgkmcnt(0)" ::: "memory");
    else
      asm volatile("s_waitcnt vmcnt(0) lgkmcnt(0)" ::: "memory");
    __builtin_amdgcn_s_barrier();

    if (t + 1 < NT) {   // pack A(t+1) -> As[(t+1)&1] (regs drained by vmcnt above)
      uint2 p0, p1;
      p0.x = pack2bf16(c0.x, c0.y); p0.y = pack2bf16(c0.z, c0.w);
      p1.x = pack2bf16(c1.x, c1.y); p1.y = pack2bf16(c1.z, c1.w);
      *(uint2*)((char*)As + ((t + 1) & 1) * 8192 + ao0) = p0;
      *(uint2*)((char*)As + ((t + 1) & 1) * 8192 + ao1) = p1;
    }
    if (t + 2 < NT) {   // issue A(t+2) FIRST, then B(t+2) (FIFO discipline)
      c0 = *(const float4*)ap;
      c1 = *(const float4*)(ap + 16);
      ap += BK;
      if (((t + 3) & 15) == 0) ap += (size_t)NBLK * BM * DK - DK;   // next m-tile
      asm volatile("" ::: "memory");   // pin A-loads ahead of B-DMA in vmcnt FIFO
      int wrB = rdB + 2; if (wrB >= 3) wrB -= 3;
      const int itn = (t + 2) & 15;    // B depends only on k-iter (same panel each tile)
#pragma unroll
      for (int j = 0; j < 4; ++j)
        gll16((const void*)(bconst[j] + itn * 16384),
              (void*)((char*)Bs + wrB * 32768 + bdst[j]));
    }

    // ---- frag reads (2-way max bank aliasing = free) + MFMA ----
    const char* Abase = (const char*)As + (t & 1) * 8192;
    const char* Bbase = (const char*)Bs + rdB * 32768;
    bf16x8 af[4];
#pragma unroll
    for (int ms = 0; ms < 4; ++ms) af[ms] = *(const bf16x8*)(Abase + a_ro + ms * 1024);
#pragma unroll
    for (int h = 0; h < 2; ++h) {    // two B-halves of 4 frags: caps live VGPRs
      bf16x8 bh[4];
#pragma unroll
      for (int j = 0; j < 4; ++j)
        bh[j] = *(const bf16x8*)(Bbase + b_ro + (h * 4 + j) * 1024);
#pragma unroll
      for (int ms = 0; ms < 4; ++ms)
#pragma unroll
        for (int j = 0; j < 4; ++j)
          acc[ms][h * 4 + j] = __builtin_amdgcn_mfma_f32_16x16x32_bf16(
              af[ms], bh[j], acc[ms][h * 4 + j], 0, 0, 0);
    }

    // ---- per-tile epilogue: tanh(acc + qpb) * v, reduce 512 cols -> 128 rows ----
    if ((t & 15) == 15) {
      const int tile  = bid + (t >> 4) * NBLK;
      const int b_idx = tile >> 5;          // 32 tiles per batch
      float qv[8];
#pragma unroll
      for (int ns = 0; ns < 8; ++ns) qv[ns] = qpb[b_idx * NA + wc * 128 + ns * 16 + r16];
#pragma unroll
      for (int ms = 0; ms < 4; ++ms) {
#pragma unroll
        for (int reg = 0; reg < 4; ++reg) {
          float s = 0.f;
#pragma unroll
          for (int ns = 0; ns < 8; ++ns) {
            float x = acc[ms][ns][reg] + qv[ns];
            s = fmaf(fast_tanh(x), vv[ns], s);
          }
          // C/D row = quad*4+reg; its 16 cols live in this quad's lanes
          s += __shfl_xor(s, 1);
          s += __shfl_xor(s, 2);
          s += __shfl_xor(s, 4);
          s += __shfl_xor(s, 8);
          if (r16 == 0) part[wc][wr * 64 + ms * 16 + quad * 4 + reg] = s;
        }
      }
      asm volatile("s_waitcnt lgkmcnt(0)" ::: "memory");   // part visible; B-DMA stays in flight
      __builtin_amdgcn_s_barrier();
      if (tid < BM) {
        float s = part[0][tid] + part[1][tid] + part[2][tid] + part[3][tid];
        out[(size_t)tile * BM + tid] = s;
      }
#pragma unroll
      for (int i = 0; i < 4; ++i)
#pragma unroll
        for (int j = 0; j < 8; ++j) { f32x4 z = {0.f, 0.f, 0.f, 0.f}; acc[i][j] = z; }
    }
    rdB += 1; if (rdB == 3) rdB = 0;
  }
}

extern "C" void kernel_launch(void* const* d_in, const int* in_sizes, int n_in,
                              void* d_out, int out_size, void* d_ws, size_t ws_size,
                              hipStream_t stream) {
  const float* q = (const float*)d_in[0];
  const float* k = (const float*)d_in[1];
  const float* W = (const float*)d_in[2];
  const float* b = (const float*)d_in[3];
  const float* v = (const float*)d_in[4];
  float* out = (float*)d_out;

  // ws: [0,64KB) qpb fp32; [64KB,576KB) WkTt bf16 (tiled)
  float* qpb = (float*)d_ws;
  uint16_t* WkTt = (uint16_t*)((char*)d_ws + 65536);

  prep_kernel<<<320, 256, 0, stream>>>(W, q, b, WkTt, qpb);
  score_kernel<<<NBLK, 512, 0, stream>>>(k, WkTt, qpb, v, out);
}